// Round 4
// baseline (236.914 us; speedup 1.0000x reference)
//
#include <hip/hip_runtime.h>

// KAN layer: out[b,o] = sum_i phi[b,i] * wsum[o,i]
//   phi[b,i]  = b2[i] + sum_h w2[i,h] * silu(x[b,i]*w1[i,h] + b1[i,h])
//   wsum[o,i] = sum_k weights[o,i,k]
// B=32768, I=256, O=256, NB=256, H=16

#define B_DIM 32768
#define I_DIM 256
#define O_DIM 256
#define NB_DIM 256
#define H_DIM 16

typedef __bf16 bf16x8 __attribute__((ext_vector_type(8)));
typedef float f32x4 __attribute__((ext_vector_type(4)));

#define NWSUM_BLOCKS (O_DIM * I_DIM / 4)          // 16384: 4 waves/block, 1 (o,i) pair per wave
#define NPHI_BLOCKS (B_DIM * I_DIM / 256)         // 32768: 1 phi element per thread

// Phase 1+2 fused launch: blockIdx%3==0 -> wsum reduction (HBM-bound),
// else -> phi MLP (transcendental-bound). Interleaving makes both kinds
// co-resident so HBM reads hide under VALU work (m114: pipes overlap).
__global__ __launch_bounds__(256) void k_prep(
    const float* __restrict__ wt,   // [O, I, NB]
    const float* __restrict__ x,    // [B, I]
    const float* __restrict__ w1,   // [I, H]
    const float* __restrict__ b1,   // [I, H]
    const float* __restrict__ w2,   // [I, H]
    const float* __restrict__ b2,   // [I]
    __bf16* __restrict__ wsum,      // [O, I]  (== [N, K] for the GEMM)
    __bf16* __restrict__ phi)       // [B, I]  (== [M, K])
{
    const unsigned b = blockIdx.x;
    if (b % 3u == 0u) {
        // ---- wsum: one wave reduces one (o,i) pair's 256 contiguous floats ----
        const int wave = threadIdx.x >> 6;
        const int lane = threadIdx.x & 63;
        const int p = (int)(b / 3u) * 4 + wave;           // p = o*I + i, < 65536
        float4 v = ((const float4*)(wt + (size_t)p * NB_DIM))[lane];
        float s = (v.x + v.y) + (v.z + v.w);
        #pragma unroll
        for (int off = 32; off; off >>= 1) s += __shfl_down(s, off, 64);
        if (lane == 0) wsum[p] = (__bf16)s;
    } else {
        // ---- phi: one thread computes one (b,i) via the 16-wide MLP ----
        const int idx = (int)(b - b / 3u - 1u) * 256 + (int)threadIdx.x;
        const int i = idx & (I_DIM - 1);
        const float xv = x[idx];
        const float4* w1v = (const float4*)(w1 + i * H_DIM);
        const float4* b1v = (const float4*)(b1 + i * H_DIM);
        const float4* w2v = (const float4*)(w2 + i * H_DIM);
        float acc = b2[i];
        #pragma unroll
        for (int q = 0; q < 4; ++q) {
            float4 a = w1v[q], c = b1v[q], d = w2v[q];
            float z, sg;
            // silu(z) = z / (1 + exp(-z)) = z * rcp(1 + exp2(-z*log2e))
            z = fmaf(xv, a.x, c.x);
            sg = __builtin_amdgcn_rcpf(1.0f + __builtin_amdgcn_exp2f(z * -1.44269504f));
            acc = fmaf(z * sg, d.x, acc);
            z = fmaf(xv, a.y, c.y);
            sg = __builtin_amdgcn_rcpf(1.0f + __builtin_amdgcn_exp2f(z * -1.44269504f));
            acc = fmaf(z * sg, d.y, acc);
            z = fmaf(xv, a.z, c.z);
            sg = __builtin_amdgcn_rcpf(1.0f + __builtin_amdgcn_exp2f(z * -1.44269504f));
            acc = fmaf(z * sg, d.z, acc);
            z = fmaf(xv, a.w, c.w);
            sg = __builtin_amdgcn_rcpf(1.0f + __builtin_amdgcn_exp2f(z * -1.44269504f));
            acc = fmaf(z * sg, d.w, acc);
        }
        phi[idx] = (__bf16)acc;
    }
}

// Phase 3: out[b,o] = phi[b,:] . wsum[o,:]  (A [M,K] x B^T [N,K], K=256)
// Block = 256 thr = 4 waves as 2x2; wave tile 64x64 = 4x4 frags of 16x16x32.
// No LDS: wsum (128 KB) is L2-resident; phi streams through L2. 8 16B
// fragment loads per 16 MFMAs.
__global__ __launch_bounds__(256) void k_gemm(
    const __bf16* __restrict__ phi,   // [B, I]
    const __bf16* __restrict__ wsum,  // [O, I]
    float* __restrict__ out)          // [B, O]
{
    const int lane = threadIdx.x & 63;
    const int wave = threadIdx.x >> 6;
    const int m0 = blockIdx.x * 128 + (wave >> 1) * 64;
    const int n0 = blockIdx.y * 128 + (wave & 1) * 64;
    const int rowsel = lane & 15;           // A row / B^T row within 16x16 frag
    const int ksel = (lane >> 4) * 8;       // k offset within 32-slice

    f32x4 acc[4][4] = {};
    for (int k0 = 0; k0 < I_DIM; k0 += 32) {
        bf16x8 a[4], bfrag[4];
        #pragma unroll
        for (int t = 0; t < 4; ++t) {
            a[t] = *(const bf16x8*)(phi + (size_t)(m0 + t * 16 + rowsel) * I_DIM + k0 + ksel);
            bfrag[t] = *(const bf16x8*)(wsum + (size_t)(n0 + t * 16 + rowsel) * I_DIM + k0 + ksel);
        }
        #pragma unroll
        for (int mi = 0; mi < 4; ++mi)
            #pragma unroll
            for (int ni = 0; ni < 4; ++ni)
                acc[mi][ni] = __builtin_amdgcn_mfma_f32_16x16x32_bf16(
                    a[mi], bfrag[ni], acc[mi][ni], 0, 0, 0);
    }

    // C/D layout: col = lane&15 (N), row = (lane>>4)*4 + r (M)   [m89/m91]
    const int r0 = (lane >> 4) * 4;
    const int c = lane & 15;
    #pragma unroll
    for (int mi = 0; mi < 4; ++mi)
        #pragma unroll
        for (int ni = 0; ni < 4; ++ni)
            #pragma unroll
            for (int r = 0; r < 4; ++r)
                out[(size_t)(m0 + mi * 16 + r0 + r) * O_DIM + n0 + ni * 16 + c] =
                    acc[mi][ni][r];
}

extern "C" void kernel_launch(void* const* d_in, const int* in_sizes, int n_in,
                              void* d_out, int out_size, void* d_ws, size_t ws_size,
                              hipStream_t stream) {
    const float* x  = (const float*)d_in[0];
    const float* wt = (const float*)d_in[1];
    const float* w1 = (const float*)d_in[2];
    const float* b1 = (const float*)d_in[3];
    const float* w2 = (const float*)d_in[4];
    const float* b2 = (const float*)d_in[5];
    float* out = (float*)d_out;

    // workspace layout: wsum bf16 [O*I] at 0 (128 KB), phi bf16 [B*I] at 256 KB
    __bf16* wsum = (__bf16*)d_ws;
    __bf16* phi  = (__bf16*)((char*)d_ws + 256 * 1024);

    hipLaunchKernelGGL(k_prep, dim3(NWSUM_BLOCKS + NPHI_BLOCKS), dim3(256), 0, stream,
                       wt, x, w1, b1, w2, b2, wsum, phi);
    hipLaunchKernelGGL(k_gemm, dim3(B_DIM / 128, O_DIM / 128), dim3(256), 0, stream,
                       phi, wsum, out);
}

// Round 7
// 189.200 us; speedup vs baseline: 1.2522x; 1.2522x over previous
//
#include <hip/hip_runtime.h>

// KAN layer: out[b,o] = sum_i phi[b,i] * wsum[o,i]
//   phi[b,i]  = b2[i] + sum_h w2[i,h] * silu(x[b,i]*w1[i,h] + b1[i,h])
//   wsum[o,i] = sum_k weights[o,i,k]
// B=32768, I=256, O=256, NB=256, H=16

#define B_DIM 32768
#define I_DIM 256
#define O_DIM 256
#define NB_DIM 256

typedef __bf16 bf16x8 __attribute__((ext_vector_type(8)));
typedef float f32x4 __attribute__((ext_vector_type(4)));

// ================= k_prep: fused wsum-pack + phi MLP =================
// 5120 blocks of 256 thr. b%5==0 -> phi block (1024 total, 32 rows each);
// else -> wsum block (4096 total, 16 (o,i) pairs each). Interleaved so the
// HBM-heavy wsum waves overlap the TRANS-heavy phi waves (m114).
//
// wsum is written PACKED in MFMA B-fragment order ("wpack") so k_gemm's
// B loads are lane-contiguous 16B (no gathers):
//   wpack[(((o>>4)*8 + (i>>5))*64 + (o&15) + (((i>>3)&3)<<4))*8 + (i&7)]
__global__ __launch_bounds__(256) void k_prep(
    const float* __restrict__ wt,   // [O, I, NB]
    const float* __restrict__ x,    // [B, I]
    const float* __restrict__ w1,   // [I, 16]
    const float* __restrict__ b1,   // [I, 16]
    const float* __restrict__ w2,   // [I, 16]
    const float* __restrict__ b2,   // [I]
    __bf16* __restrict__ wpack,     // [65536] packed B fragments
    __bf16* __restrict__ phi)       // [B, I] row-major (linear)
{
    const unsigned b = blockIdx.x;
    if (b % 5u == 0u) {
        // ---- phi: thread owns column i = tid, loops 32 batch rows.
        // Weights live in registers: 12 gather-loads amortized over 32 rows.
        const int i = (int)threadIdx.x;
        float w1r[16], b1r[16], w2r[16];
        #pragma unroll
        for (int q = 0; q < 4; ++q) {
            const float4 a = ((const float4*)(w1 + i * 16))[q];
            const float4 c = ((const float4*)(b1 + i * 16))[q];
            const float4 d = ((const float4*)(w2 + i * 16))[q];
            w1r[q*4+0] = a.x; w1r[q*4+1] = a.y; w1r[q*4+2] = a.z; w1r[q*4+3] = a.w;
            b1r[q*4+0] = c.x; b1r[q*4+1] = c.y; b1r[q*4+2] = c.z; b1r[q*4+3] = c.w;
            w2r[q*4+0] = d.x; w2r[q*4+1] = d.y; w2r[q*4+2] = d.z; w2r[q*4+3] = d.w;
        }
        const float b2r = b2[i];
        const int r0 = (int)(b / 5u) * 32;
        float xv = x[(size_t)r0 * I_DIM + i];          // coalesced (lane=i)
        for (int rr = 0; rr < 32; ++rr) {
            const int r = r0 + rr;
            const float xn = (rr < 31) ? x[(size_t)(r + 1) * I_DIM + i] : 0.0f;
            float acc = b2r;
            #pragma unroll
            for (int h = 0; h < 16; ++h) {
                const float z = fmaf(xv, w1r[h], b1r[h]);
                const float sg = __builtin_amdgcn_rcpf(
                    1.0f + __builtin_amdgcn_exp2f(z * -1.44269504f));
                acc = fmaf(z * sg, w2r[h], acc);
            }
            phi[(size_t)r * I_DIM + i] = (__bf16)acc;  // coalesced 2B/lane
            xv = xn;
        }
    } else {
        // ---- wsum: one wave reduces one (o,i) pair's 256 floats; 4 pairs/wave.
        const unsigned wb = b - b / 5u - 1u;           // 0..4095
        const int wave = (int)(threadIdx.x >> 6);
        const int lane = (int)(threadIdx.x & 63u);
        const int pbase = ((int)wb * 4 + wave) * 4;
        #pragma unroll
        for (int j = 0; j < 4; ++j) {
            const int p = pbase + j;                   // p = o*256 + i
            const float4 v = ((const float4*)(wt + (size_t)p * NB_DIM))[lane];
            float s = (v.x + v.y) + (v.z + v.w);
            #pragma unroll
            for (int off = 32; off; off >>= 1) s += __shfl_down(s, off, 64);
            if (lane == 0) {
                const int o = p >> 8, ii = p & 255;
                const int l = (o & 15) + (((ii >> 3) & 3) << 4);
                wpack[(size_t)((((o >> 4) * 8 + (ii >> 5)) * 64) + l) * 8 + (ii & 7)] =
                    (__bf16)s;
            }
        }
    }
}

// ================= k_gemm: out = phi @ wsum^T =================
// Grid 512 blocks (M-tile 64) x 512 thr (8 waves as 2Mx4N; wave tile 32x64).
// A: 64x256 bf16 phi tile staged to LDS with XOR swizzle (write AND read side:
//   byte ^= ((row&7)<<4) -> ds_read_b128 is ~conflict-free by construction).
// B: read from L2-resident wpack, lane-contiguous 16B (coalesced, no gathers).
__global__ __launch_bounds__(512) void k_gemm(
    const __bf16* __restrict__ phi,    // [B, I] linear
    const __bf16* __restrict__ wpack,  // packed B fragments
    float* __restrict__ out)           // [B, O]
{
    __shared__ uint4 atile4[2048];     // 32 KB: 64 rows x 512 B, swizzled
    char* atile = (char*)atile4;
    const int tid = (int)threadIdx.x;
    const int lane = tid & 63, wave = tid >> 6;
    const int wm = wave >> 2, wn = wave & 3;

    // Stage phi tile: 4 iters x 512 thr x 16B = 32 KB. Linear global read,
    // swizzled LDS write (both sides of the swizzle are in this kernel).
    const char* src = (const char*)phi + (size_t)blockIdx.x * 32768;
    #pragma unroll
    for (int it = 0; it < 4; ++it) {
        const int off = it * 8192 + tid * 16;
        const uint4 v = *(const uint4*)(src + off);
        const int swz = off ^ (((off >> 9) & 7) << 4);
        *(uint4*)(atile + swz) = v;
    }
    __syncthreads();

    const int rowsel = lane & 15;
    const int kgrp = lane >> 4;                        // 0..3
    f32x4 acc[2][4] = {};
    #pragma unroll
    for (int kx = 0; kx < 8; ++kx) {                   // k0 = kx*32
        bf16x8 a[2], bb[4];
        #pragma unroll
        for (int t = 0; t < 2; ++t) {
            const int r = wm * 32 + t * 16 + rowsel;
            const int i0 = kx * 32 + kgrp * 8;
            const int boff = (r << 9) + (((i0 << 1)) ^ ((r & 7) << 4));
            a[t] = *(const bf16x8*)(atile + boff);     // ds_read_b128
        }
        #pragma unroll
        for (int t = 0; t < 4; ++t) {
            const int nf = wn * 4 + t;
            bb[t] = *(const bf16x8*)(wpack + (size_t)(((nf * 8 + kx) * 64) + lane) * 8);
        }
        #pragma unroll
        for (int mi = 0; mi < 2; ++mi)
            #pragma unroll
            for (int ni = 0; ni < 4; ++ni)
                acc[mi][ni] = __builtin_amdgcn_mfma_f32_16x16x32_bf16(
                    a[mi], bb[ni], acc[mi][ni], 0, 0, 0);
    }

    // C/D layout: col = lane&15, row = (lane>>4)*4 + reg  [m89/m91]
    const int m_base = (int)blockIdx.x * 64 + wm * 32;
    const int n_base = wn * 64;
    const int r0 = (lane >> 4) * 4, c = lane & 15;
    #pragma unroll
    for (int mi = 0; mi < 2; ++mi)
        #pragma unroll
        for (int ni = 0; ni < 4; ++ni)
            #pragma unroll
            for (int rr = 0; rr < 4; ++rr)
                out[(size_t)(m_base + mi * 16 + r0 + rr) * O_DIM + n_base + ni * 16 + c] =
                    acc[mi][ni][rr];
}

extern "C" void kernel_launch(void* const* d_in, const int* in_sizes, int n_in,
                              void* d_out, int out_size, void* d_ws, size_t ws_size,
                              hipStream_t stream) {
    const float* x  = (const float*)d_in[0];
    const float* wt = (const float*)d_in[1];
    const float* w1 = (const float*)d_in[2];
    const float* b1 = (const float*)d_in[3];
    const float* w2 = (const float*)d_in[4];
    const float* b2 = (const float*)d_in[5];
    float* out = (float*)d_out;

    // ws layout: wpack bf16 [65536] at 0 (128 KB), phi bf16 [B*I] at 256 KB (16 MB)
    __bf16* wpack = (__bf16*)d_ws;
    __bf16* phi   = (__bf16*)((char*)d_ws + 256 * 1024);

    hipLaunchKernelGGL(k_prep, dim3(5120), dim3(256), 0, stream,
                       wt, x, w1, b1, w2, b2, wpack, phi);
    hipLaunchKernelGGL(k_gemm, dim3(512), dim3(512), 0, stream,
                       phi, wpack, out);
}

// Round 9
// 170.909 us; speedup vs baseline: 1.3862x; 1.1070x over previous
//
#include <hip/hip_runtime.h>

// KAN layer: out[b,o] = sum_i phi[b,i] * wsum[o,i]
//   phi[b,i]  = b2[i] + sum_h w2[i,h] * silu(x[b,i]*w1[i,h] + b1[i,h])
//   wsum[o,i] = sum_k weights[o,i,k]
// B=32768, I=256, O=256, NB=256, H=16

#define B_DIM 32768
#define I_DIM 256
#define O_DIM 256
#define NB_DIM 256

typedef __bf16 bf16x8 __attribute__((ext_vector_type(8)));
typedef float f32x4 __attribute__((ext_vector_type(4)));

// wpack layout (MFMA B-fragment order so GEMM B-loads are lane-contiguous):
//   for (o,i): frag = (o>>4)*8 + (i>>5); lane = (o&15) | (((i>>3)&3)<<4);
//   reg = i&7; index = (frag*64 + lane)*8 + reg
__device__ __forceinline__ size_t wpack_idx(int o, int ii) {
    const int l = (o & 15) | (((ii >> 3) & 3) << 4);
    return (size_t)((((o >> 4) * 8 + (ii >> 5)) * 64) + l) * 8 + (ii & 7);
}

// ============ k_wsum: wave-per-(o,i) reduction of weights[o,i,:] ============
// 4096 blocks x 256 thr; wave reduces 4 pairs (coalesced float4 row reads).
__global__ __launch_bounds__(256) void k_wsum(
    const float* __restrict__ wt,   // [O, I, NB]
    __bf16* __restrict__ wpack)     // [65536] packed B fragments
{
    const int wave = (int)(threadIdx.x >> 6);
    const int lane = (int)(threadIdx.x & 63u);
    const int pbase = ((int)blockIdx.x * 4 + wave) * 4;
    #pragma unroll
    for (int j = 0; j < 4; ++j) {
        const int p = pbase + j;                       // p = o*256 + i
        const float4 v = ((const float4*)(wt + (size_t)p * NB_DIM))[lane];
        float s = (v.x + v.y) + (v.z + v.w);
        #pragma unroll
        for (int off = 32; off; off >>= 1) s += __shfl_down(s, off, 64);
        if (lane == 0) wpack[wpack_idx(p >> 8, p & 255)] = (__bf16)s;
    }
}

// ============ k_fused: phi tile in LDS -> MFMA GEMM ============
// 512 blocks x 512 thr (8 waves). Block owns 64 output rows.
// Phase 1: thread owns column i = tid&255, half = tid>>8 -> 32 rows; weights
//   in NAMED float4 regs (launch_bounds(512,4) => 128-VGPR budget, no scratch).
//   phi written bf16 into XOR-swizzled LDS (write side coalesced in i).
// Phase 2: 8 waves as 2M x 4N (wave tile 32x64); A from swizzled LDS
//   ds_read_b128, B lane-contiguous 16B from L2-resident wpack.
__global__ __launch_bounds__(512, 4) void k_fused(
    const float* __restrict__ x,    // [B, I]
    const float* __restrict__ w1,   // [I, 16]
    const float* __restrict__ b1,   // [I, 16]
    const float* __restrict__ w2,   // [I, 16]
    const float* __restrict__ b2,   // [I]
    const __bf16* __restrict__ wpack,
    float* __restrict__ out)        // [B, O]
{
    __shared__ uint4 atile4[2048];  // 32 KB: 64 rows x 512 B, XOR-swizzled
    char* atile = (char*)atile4;
    const int tid = (int)threadIdx.x;

    // ---------------- Phase 1: phi ----------------
    {
        const int i = tid & 255;
        const int half = tid >> 8;                     // 0/1 -> rows 0-31 / 32-63
        const float4* w1v = (const float4*)(w1 + i * 16);
        const float4* b1v = (const float4*)(b1 + i * 16);
        const float4* w2v = (const float4*)(w2 + i * 16);
        const float4 w1a = w1v[0], w1b = w1v[1], w1c = w1v[2], w1d = w1v[3];
        const float4 b1a = b1v[0], b1b = b1v[1], b1c = b1v[2], b1d = b1v[3];
        const float4 w2a = w2v[0], w2b = w2v[1], w2c = w2v[2], w2d = w2v[3];
        const float b2r = b2[i];
        const size_t xbase = (size_t)((int)blockIdx.x * 64 + half * 32) * I_DIM + i;

        for (int rr = 0; rr < 32; rr += 2) {           // 2 rows -> 2 indep chains
            const float xv0 = x[xbase + (size_t)rr * I_DIM];
            const float xv1 = x[xbase + (size_t)(rr + 1) * I_DIM];
            float acc0 = b2r, acc1 = b2r;
#define KAN_STEP(WV, BV, DV)                                                   \
            {                                                                  \
                float z0 = fmaf(xv0, WV, BV), z1 = fmaf(xv1, WV, BV);          \
                float s0 = __builtin_amdgcn_rcpf(                              \
                    1.0f + __builtin_amdgcn_exp2f(z0 * -1.44269504f));         \
                float s1 = __builtin_amdgcn_rcpf(                              \
                    1.0f + __builtin_amdgcn_exp2f(z1 * -1.44269504f));         \
                acc0 = fmaf(z0 * s0, DV, acc0);                                \
                acc1 = fmaf(z1 * s1, DV, acc1);                                \
            }
            KAN_STEP(w1a.x, b1a.x, w2a.x) KAN_STEP(w1a.y, b1a.y, w2a.y)
            KAN_STEP(w1a.z, b1a.z, w2a.z) KAN_STEP(w1a.w, b1a.w, w2a.w)
            KAN_STEP(w1b.x, b1b.x, w2b.x) KAN_STEP(w1b.y, b1b.y, w2b.y)
            KAN_STEP(w1b.z, b1b.z, w2b.z) KAN_STEP(w1b.w, b1b.w, w2b.w)
            KAN_STEP(w1c.x, b1c.x, w2c.x) KAN_STEP(w1c.y, b1c.y, w2c.y)
            KAN_STEP(w1c.z, b1c.z, w2c.z) KAN_STEP(w1c.w, b1c.w, w2c.w)
            KAN_STEP(w1d.x, b1d.x, w2d.x) KAN_STEP(w1d.y, b1d.y, w2d.y)
            KAN_STEP(w1d.z, b1d.z, w2d.z) KAN_STEP(w1d.w, b1d.w, w2d.w)
#undef KAN_STEP
            const int rl0 = half * 32 + rr, rl1 = rl0 + 1;
            const int a0 = (rl0 * 512 + i * 2) ^ ((rl0 & 7) << 4);
            const int a1 = (rl1 * 512 + i * 2) ^ ((rl1 & 7) << 4);
            *(__bf16*)(atile + a0) = (__bf16)acc0;     // ds_write_b16, coalesced in i
            *(__bf16*)(atile + a1) = (__bf16)acc1;
        }
    }
    __syncthreads();

    // ---------------- Phase 2: GEMM ----------------
    const int lane = tid & 63, wave = tid >> 6;
    const int wm = wave >> 2, wn = wave & 3;           // 2M x 4N
    const int rowsel = lane & 15;
    const int kgrp = lane >> 4;                        // 0..3

    f32x4 acc[2][4] = {};
    #pragma unroll
    for (int kx = 0; kx < 8; ++kx) {                   // k0 = kx*32
        bf16x8 a[2], bb[4];
        #pragma unroll
        for (int t = 0; t < 2; ++t) {
            const int r = wm * 32 + t * 16 + rowsel;
            const int boff = (r << 9) + ((kx * 64 + kgrp * 16) ^ ((r & 7) << 4));
            a[t] = *(const bf16x8*)(atile + boff);     // ds_read_b128, ~conflict-free
        }
        #pragma unroll
        for (int t = 0; t < 4; ++t) {
            const int nf = wn * 4 + t;                 // 0..15
            bb[t] = *(const bf16x8*)(wpack + (size_t)(((nf * 8 + kx) * 64) + lane) * 8);
        }
        #pragma unroll
        for (int mi = 0; mi < 2; ++mi)
            #pragma unroll
            for (int ni = 0; ni < 4; ++ni)
                acc[mi][ni] = __builtin_amdgcn_mfma_f32_16x16x32_bf16(
                    a[mi], bb[ni], acc[mi][ni], 0, 0, 0);
    }

    // C/D layout: col = lane&15, row = (lane>>4)*4 + reg  [m89/m91]
    const int m_base = (int)blockIdx.x * 64 + wm * 32;
    const int n_base = wn * 64;
    const int r0 = (lane >> 4) * 4, c = lane & 15;
    #pragma unroll
    for (int mi = 0; mi < 2; ++mi)
        #pragma unroll
        for (int ni = 0; ni < 4; ++ni)
            #pragma unroll
            for (int rr = 0; rr < 4; ++rr)
                out[(size_t)(m_base + mi * 16 + r0 + rr) * O_DIM + n_base + ni * 16 + c] =
                    acc[mi][ni][rr];
}

extern "C" void kernel_launch(void* const* d_in, const int* in_sizes, int n_in,
                              void* d_out, int out_size, void* d_ws, size_t ws_size,
                              hipStream_t stream) {
    const float* x  = (const float*)d_in[0];
    const float* wt = (const float*)d_in[1];
    const float* w1 = (const float*)d_in[2];
    const float* b1 = (const float*)d_in[3];
    const float* w2 = (const float*)d_in[4];
    const float* b2 = (const float*)d_in[5];
    float* out = (float*)d_out;

    __bf16* wpack = (__bf16*)d_ws;                     // 128 KB

    hipLaunchKernelGGL(k_wsum, dim3(4096), dim3(256), 0, stream, wt, wpack);
    hipLaunchKernelGGL(k_fused, dim3(512), dim3(512), 0, stream,
                       x, w1, b1, w2, b2, wpack, out);
}

// Round 10
// 166.610 us; speedup vs baseline: 1.4220x; 1.0258x over previous
//
#include <hip/hip_runtime.h>

// KAN layer: out[b,o] = sum_i phi[b,i] * wsum[o,i]
//   phi[b,i]  = b2[i] + sum_h w2[i,h] * silu(x[b,i]*w1[i,h] + b1[i,h])
//   wsum[o,i] = sum_k weights[o,i,k]
// B=32768, I=256, O=256, NB=256, H=16

#define B_DIM 32768
#define I_DIM 256
#define O_DIM 256
#define NB_DIM 256

typedef __bf16 bf16x8 __attribute__((ext_vector_type(8)));
typedef float f32x4 __attribute__((ext_vector_type(4)));

// wpack layout (MFMA B-fragment order so GEMM B-loads are lane-contiguous):
//   for (o,i): frag = (o>>4)*8 + (i>>5); lane = (o&15) | (((i>>3)&3)<<4);
//   reg = i&7; index = (frag*64 + lane)*8 + reg
__device__ __forceinline__ size_t wpack_idx(int o, int ii) {
    const int l = (o & 15) | (((ii >> 3) & 3) << 4);
    return (size_t)((((o >> 4) * 8 + (ii >> 5)) * 64) + l) * 8 + (ii & 7);
}

// ============ k_wsum: 8 rows per wave, ILP-batched ============
// 2048 blocks x 256 thr (4 waves). Wave: 8 independent coalesced float4 row
// reads up-front (8 KB in flight), then 8 interleaved butterfly chains
// (shuffle latency hidden by 8-way ILP) -> BW-bound by construction.
__global__ __launch_bounds__(256) void k_wsum(
    const float* __restrict__ wt,   // [O, I, NB]
    __bf16* __restrict__ wpack)     // [65536] packed B fragments
{
    const int wave = (int)(threadIdx.x >> 6);
    const int lane = (int)(threadIdx.x & 63u);
    const int p0 = ((int)blockIdx.x * 4 + wave) * 8;
    float s[8];
    #pragma unroll
    for (int j = 0; j < 8; ++j) {
        const float4 v = ((const float4*)(wt + (size_t)(p0 + j) * NB_DIM))[lane];
        s[j] = (v.x + v.y) + (v.z + v.w);
    }
    #pragma unroll
    for (int off = 32; off; off >>= 1) {
        #pragma unroll
        for (int j = 0; j < 8; ++j) s[j] += __shfl_down(s[j], off, 64);
    }
    if (lane == 0) {
        #pragma unroll
        for (int j = 0; j < 8; ++j) {
            const int p = p0 + j;
            wpack[wpack_idx(p >> 8, p & 255)] = (__bf16)s[j];
        }
    }
}

// ============ k_fused: phi tile in LDS -> MFMA GEMM ============
// 1024 blocks x 512 thr (8 waves), M-tile 32 -> 4 blocks/CU (32 waves = full
// occupancy at VGPR<=64). Phase 1: thread owns col i = tid&255, 16 rows,
// weights in NAMED float4 regs, 2-row ILP; phi -> XOR-swizzled LDS (bf16).
// Phase 2: 8 waves each own a 32-col N-strip; wave tile 32x32 = 2x2 frags;
// A from swizzled LDS ds_read_b128, B lane-contiguous 16B from L2 wpack.
__global__ __launch_bounds__(512, 8) void k_fused(
    const float* __restrict__ x,    // [B, I]
    const float* __restrict__ w1,   // [I, 16]
    const float* __restrict__ b1,   // [I, 16]
    const float* __restrict__ w2,   // [I, 16]
    const float* __restrict__ b2,   // [I]
    const __bf16* __restrict__ wpack,
    float* __restrict__ out)        // [B, O]
{
    __shared__ uint4 atile4[1024];  // 16 KB: 32 rows x 512 B, XOR-swizzled
    char* atile = (char*)atile4;
    const int tid = (int)threadIdx.x;

    // ---------------- Phase 1: phi (16 rows/thread) ----------------
    {
        const int i = tid & 255;
        const int half = tid >> 8;                     // 0/1 -> rows 0-15 / 16-31
        const float4* w1v = (const float4*)(w1 + i * 16);
        const float4* b1v = (const float4*)(b1 + i * 16);
        const float4* w2v = (const float4*)(w2 + i * 16);
        const float4 w1a = w1v[0], w1b = w1v[1], w1c = w1v[2], w1d = w1v[3];
        const float4 b1a = b1v[0], b1b = b1v[1], b1c = b1v[2], b1d = b1v[3];
        const float4 w2a = w2v[0], w2b = w2v[1], w2c = w2v[2], w2d = w2v[3];
        const float b2r = b2[i];
        const size_t xbase = (size_t)((int)blockIdx.x * 32 + half * 16) * I_DIM + i;

        for (int rr = 0; rr < 16; rr += 2) {           // 2 rows -> 2 indep chains
            const float xv0 = x[xbase + (size_t)rr * I_DIM];
            const float xv1 = x[xbase + (size_t)(rr + 1) * I_DIM];
            float acc0 = b2r, acc1 = b2r;
#define KAN_STEP(WV, BV, DV)                                                   \
            {                                                                  \
                float z0 = fmaf(xv0, WV, BV), z1 = fmaf(xv1, WV, BV);          \
                float s0 = __builtin_amdgcn_rcpf(                              \
                    1.0f + __builtin_amdgcn_exp2f(z0 * -1.44269504f));         \
                float s1 = __builtin_amdgcn_rcpf(                              \
                    1.0f + __builtin_amdgcn_exp2f(z1 * -1.44269504f));         \
                acc0 = fmaf(z0 * s0, DV, acc0);                                \
                acc1 = fmaf(z1 * s1, DV, acc1);                                \
            }
            KAN_STEP(w1a.x, b1a.x, w2a.x) KAN_STEP(w1a.y, b1a.y, w2a.y)
            KAN_STEP(w1a.z, b1a.z, w2a.z) KAN_STEP(w1a.w, b1a.w, w2a.w)
            KAN_STEP(w1b.x, b1b.x, w2b.x) KAN_STEP(w1b.y, b1b.y, w2b.y)
            KAN_STEP(w1b.z, b1b.z, w2b.z) KAN_STEP(w1b.w, b1b.w, w2b.w)
            KAN_STEP(w1c.x, b1c.x, w2c.x) KAN_STEP(w1c.y, b1c.y, w2c.y)
            KAN_STEP(w1c.z, b1c.z, w2c.z) KAN_STEP(w1c.w, b1c.w, w2c.w)
            KAN_STEP(w1d.x, b1d.x, w2d.x) KAN_STEP(w1d.y, b1d.y, w2d.y)
            KAN_STEP(w1d.z, b1d.z, w2d.z) KAN_STEP(w1d.w, b1d.w, w2d.w)
#undef KAN_STEP
            const int rl0 = half * 16 + rr, rl1 = rl0 + 1;
            const int a0 = (rl0 * 512 + i * 2) ^ ((rl0 & 7) << 4);
            const int a1 = (rl1 * 512 + i * 2) ^ ((rl1 & 7) << 4);
            *(__bf16*)(atile + a0) = (__bf16)acc0;     // ds_write_b16, 2-way = free
            *(__bf16*)(atile + a1) = (__bf16)acc1;
        }
    }
    __syncthreads();

    // ---------------- Phase 2: GEMM (wave = 32-col N-strip) ----------------
    const int lane = tid & 63, wave = tid >> 6;        // wave 0..7
    const int rowsel = lane & 15;
    const int kgrp = lane >> 4;                        // 0..3

    f32x4 acc[2][2] = {};
    #pragma unroll
    for (int kx = 0; kx < 8; ++kx) {                   // k0 = kx*32
        bf16x8 a[2], bb[2];
        #pragma unroll
        for (int t = 0; t < 2; ++t) {
            const int r = t * 16 + rowsel;
            const int boff = r * 512 + ((kx * 64 + kgrp * 16) ^ ((r & 7) << 4));
            a[t] = *(const bf16x8*)(atile + boff);     // ds_read_b128
        }
        #pragma unroll
        for (int t = 0; t < 2; ++t) {
            const int nf = wave * 2 + t;               // 0..15
            bb[t] = *(const bf16x8*)(wpack + (size_t)(((nf * 8 + kx) * 64) + lane) * 8);
        }
        #pragma unroll
        for (int mi = 0; mi < 2; ++mi)
            #pragma unroll
            for (int ni = 0; ni < 2; ++ni)
                acc[mi][ni] = __builtin_amdgcn_mfma_f32_16x16x32_bf16(
                    a[mi], bb[ni], acc[mi][ni], 0, 0, 0);
    }

    // C/D layout: col = lane&15, row = (lane>>4)*4 + reg  [m89/m91]
    const int m_base = (int)blockIdx.x * 32;
    const int n_base = wave * 32;
    const int r0 = (lane >> 4) * 4, c = lane & 15;
    #pragma unroll
    for (int mi = 0; mi < 2; ++mi)
        #pragma unroll
        for (int ni = 0; ni < 2; ++ni)
            #pragma unroll
            for (int rr = 0; rr < 4; ++rr)
                out[(size_t)(m_base + mi * 16 + r0 + rr) * O_DIM + n_base + ni * 16 + c] =
                    acc[mi][ni][rr];
}

extern "C" void kernel_launch(void* const* d_in, const int* in_sizes, int n_in,
                              void* d_out, int out_size, void* d_ws, size_t ws_size,
                              hipStream_t stream) {
    const float* x  = (const float*)d_in[0];
    const float* wt = (const float*)d_in[1];
    const float* w1 = (const float*)d_in[2];
    const float* b1 = (const float*)d_in[3];
    const float* w2 = (const float*)d_in[4];
    const float* b2 = (const float*)d_in[5];
    float* out = (float*)d_out;

    __bf16* wpack = (__bf16*)d_ws;                     // 128 KB

    hipLaunchKernelGGL(k_wsum, dim3(2048), dim3(256), 0, stream, wt, wpack);
    hipLaunchKernelGGL(k_fused, dim3(1024), dim3(512), 0, stream,
                       x, w1, b1, w2, b2, wpack, out);
}